// Round 5
// baseline (212.164 us; speedup 1.0000x reference)
//
#include <hip/hip_runtime.h>

// B=16, T=1024, N=1024, D=256, WIN=64
// outputs (flat): R (B,T,2D) = [A@V, Q]   : 8388608 f32
//                 alignments (B,N,T) = A^T: 16777216 f32
//                 max_att (B,T)           : 16384 f32
//
// v12 = v11 (heterogeneous grid: 240 zero-stream blocks + 1024 attn blocks)
//       + occupancy play:
//  - K staged in FOUR 64-dim slices: ks[64][68] = 17.4KB (68%32==4, same
//    free bank pattern as v8's 132). LDS total 21.8KB -> 7 blocks/CU
//    (28 waves/CU vs v8/v11's 16). attn was latency-bound with both pipes
//    idle and occupancy ~35% -> more resident waves to cover barrier drains
//    and cold-miss latency. (v10 proved bigger tiles hurt; this is the
//    untested mirror direction.)
//  - post-softmax transpose barrier ELIMINATED: alignment strip stored from
//    registers (v9's verified layout: wave w stores cols t0+4w..+3 of row
//    prev+lane; 4 waves complete each 64B line). PV then depends only on
//    its own wave's p_lds rows (lgkmcnt, no barrier). 7 stage barriers, 0
//    epilogue barriers.
//  - zero-role blocks + hoisted Q->R copy unchanged from v11.

#define BB 16
#define TT 1024
#define NN 1024
#define DD 256
#define WIN 64
#define TBLK 16          // queries per attn block
#define NT 256           // 4 waves, 4 queries each
#define NZ 240           // zero-streaming blocks (16 batches x 15)

#define R_ELEMS   (16u*1024u*512u)        // 8388608
#define ALN_ELEMS (16u*1024u*1024u)       // 16777216

#define LSTR 68          // LDS row stride (floats); 68%32==4 -> free 2-way b128

__global__ __launch_bounds__(NT, 7) void attn_v12(
    const float* __restrict__ Q, const float* __restrict__ K,
    const float* __restrict__ V, const int* __restrict__ prev_in,
    float* __restrict__ out)
{
    __shared__ float ks[WIN * LSTR];        // 17408 B: K quarter-tile (64 x 64d)
    __shared__ float p_lds[TBLK][WIN + 4];  //  4352 B: probabilities [t][j]

    float* Rout   = out;
    float* aligns = out + R_ELEMS;
    float* maxatt = out + R_ELEMS + ALN_ELEMS;

    const int tid = threadIdx.x;

    // ================= role 1: zero-streaming blocks =================
    if (blockIdx.x < NZ) {
        const int zb    = blockIdx.x;
        const int b     = zb / 15;          // 15 blocks per batch
        const int chunk = zb % 15;          // 64 rows each
        const int prev  = prev_in[b];
        float4* zbase = (float4*)(aligns + (size_t)b * NN * TT);
        const float4 z = make_float4(0.f, 0.f, 0.f, 0.f);
        #pragma unroll 8
        for (int r = 0; r < 64; ++r) {
            int idx = chunk * 64 + r;          // 0..959 among non-window rows
            int n   = idx < prev ? idx : idx + WIN;
            zbase[(size_t)n * 256 + tid] = z;  // 4KB contiguous per row
        }
        return;                                // wave dies; stores drain async
    }

    // ================= role 2: attention blocks =================
    const int aid  = blockIdx.x - NZ;
    const int lane = tid & 63;
    const int w    = __builtin_amdgcn_readfirstlane(tid >> 6);  // wave 0..3
    const int b    = aid >> 6;              // 64 blocks per batch
    const int t0   = (aid & 63) * TBLK;
    const int prev = prev_in[b];

    const float* qb = Q + ((size_t)b * TT + t0 + 4 * w) * DD;   // wave-uniform base

    // ---- hoisted Q copy: warms L2 for the QK scalar stream ----
    #pragma unroll
    for (int t = 0; t < 4; ++t) {
        float4 qv = ((const float4*)(qb + t * DD))[lane];
        float* Rrow = Rout + ((size_t)b * TT + t0 + 4 * w + t) * (2 * DD);
        ((float4*)(Rrow + DD))[lane] = qv;
    }

    // ============ QK^T over four 64-d slices (small tile, 7 blocks/CU) ========
    float acc[4] = {0.f, 0.f, 0.f, 0.f};
    #pragma unroll
    for (int h = 0; h < 4; ++h) {
        if (h) __syncthreads();             // previous slice's readers done
        const float4* Ksrc = (const float4*)(K + ((size_t)b * NN + prev) * DD + h * 64);
        #pragma unroll
        for (int k = 0; k < 4; ++k) {
            int t4 = tid + k * NT;          // 0..1023 float4 chunks
            int r = t4 >> 4, c = t4 & 15;   // row 0..63, col-chunk 0..15
            float4 v = Ksrc[(size_t)r * 64 + c];
            *(float4*)&ks[r * LSTR + c * 4] = v;
        }
        __syncthreads();

        const float* qh = qb + h * 64;
        #pragma unroll
        for (int d4 = 0; d4 < 16; ++d4) {
            float4 kk = *(const float4*)&ks[lane * LSTR + d4 * 4];  // free 2-way
            #pragma unroll
            for (int t = 0; t < 4; ++t) {
                float4 q = ((const float4*)(qh + t * DD))[d4];      // wave-uniform
                acc[t] = fmaf(q.x, kk.x, fmaf(q.y, kk.y, fmaf(q.z, kk.z, fmaf(q.w, kk.w, acc[t]))));
            }
        }
    }

    // ===== softmax + argmax (wave-local), p -> LDS + strip registers =====
    float4 strip;
    #pragma unroll
    for (int tt = 0; tt < 4; ++tt) {
        float v = acc[tt] * 0.0625f;        // 1/sqrt(256)

        float m = v;
        #pragma unroll
        for (int off = 32; off; off >>= 1) m = fmaxf(m, __shfl_xor(m, off));

        float e = expf(v - m);
        float s = e;
        #pragma unroll
        for (int off = 32; off; off >>= 1) s += __shfl_xor(s, off);

        float pv = e / s;
        p_lds[4 * w + tt][lane] = pv;       // own wave reads back in PV
        ((float*)&strip)[tt] = pv;

        float av = v; int ai = lane;
        #pragma unroll
        for (int off = 32; off; off >>= 1) {
            float ov = __shfl_xor(av, off);
            int   oi = __shfl_xor(ai, off);
            if (ov > av || (ov == av && oi < ai)) { av = ov; ai = oi; }
        }
        if (lane == 0) maxatt[(size_t)b * TT + t0 + 4 * w + tt] = (float)(prev + ai);
    }

    // ===== alignment strip from registers: row prev+lane, cols t0+4w.. =====
    // 16B per lane; the block's 4 waves complete each 64B line. No barrier.
    *(float4*)(aligns + ((size_t)b * NN + prev + lane) * TT + t0 + 4 * w) = strip;

    // ================= PV direct from global (L2-hot V) ==================
    // lane = d-chunk (64 x float4 = 256 d); reads own wave's p rows (lgkmcnt
    // dependency only — no barrier).
    {
        const float4* V4 = (const float4*)(V + ((size_t)b * NN + prev) * DD);
        float4 o[4];
        #pragma unroll
        for (int t = 0; t < 4; ++t) o[t] = make_float4(0.f, 0.f, 0.f, 0.f);

        #pragma unroll 4
        for (int j4 = 0; j4 < WIN / 4; ++j4) {
            float4 p0 = *(const float4*)&p_lds[4 * w + 0][j4 * 4];  // uniform bcast
            float4 p1 = *(const float4*)&p_lds[4 * w + 1][j4 * 4];
            float4 p2 = *(const float4*)&p_lds[4 * w + 2][j4 * 4];
            float4 p3 = *(const float4*)&p_lds[4 * w + 3][j4 * 4];
            float4 v0 = V4[(size_t)(j4 * 4 + 0) * 64 + lane];
            float4 v1 = V4[(size_t)(j4 * 4 + 1) * 64 + lane];
            float4 v2 = V4[(size_t)(j4 * 4 + 2) * 64 + lane];
            float4 v3 = V4[(size_t)(j4 * 4 + 3) * 64 + lane];
            #define ACC4(o_, p_) \
                o_.x = fmaf(p_.x, v0.x, fmaf(p_.y, v1.x, fmaf(p_.z, v2.x, fmaf(p_.w, v3.x, o_.x)))); \
                o_.y = fmaf(p_.x, v0.y, fmaf(p_.y, v1.y, fmaf(p_.z, v2.y, fmaf(p_.w, v3.y, o_.y)))); \
                o_.z = fmaf(p_.x, v0.z, fmaf(p_.y, v1.z, fmaf(p_.z, v2.z, fmaf(p_.w, v3.z, o_.z)))); \
                o_.w = fmaf(p_.x, v0.w, fmaf(p_.y, v1.w, fmaf(p_.z, v2.w, fmaf(p_.w, v3.w, o_.w))));
            ACC4(o[0], p0) ACC4(o[1], p1) ACC4(o[2], p2) ACC4(o[3], p3)
            #undef ACC4
        }

        #pragma unroll
        for (int t = 0; t < 4; ++t) {
            float* Rrow = Rout + ((size_t)b * TT + t0 + 4 * w + t) * (2 * DD);
            ((float4*)Rrow)[lane] = o[t];   // A@V (Q half already written)
        }
    }
}

extern "C" void kernel_launch(void* const* d_in, const int* in_sizes, int n_in,
                              void* d_out, int out_size, void* d_ws, size_t ws_size,
                              hipStream_t stream) {
    const float* Q = (const float*)d_in[0];
    const float* K = (const float*)d_in[1];
    const float* V = (const float*)d_in[2];
    const int* prev = (const int*)d_in[3];
    float* out = (float*)d_out;

    // single launch: 240 zero-streaming blocks first, then 1024 attn blocks
    attn_v12<<<NZ + BB * TT / TBLK, NT, 0, stream>>>(Q, K, V, prev, out);
}

// Round 6
// 164.833 us; speedup vs baseline: 1.2871x; 1.2871x over previous
//
#include <hip/hip_runtime.h>

// B=16, T=1024, N=1024, D=256, WIN=64
// outputs (flat): R (B,T,2D) = [A@V, Q]   : 8388608 f32
//                 alignments (B,N,T) = A^T: 16777216 f32
//                 max_att (B,T)           : 16384 f32
//
// v13 = v11 with ONE lever: occupancy 4 -> 6 waves/SIMD.
//   v12's regression was traffic amplification (FETCH/WRITE +90MB each) from
//   its register strip-store + all-resident co-residency — NOT a refutation
//   of the occupancy theory, which it never cleanly tested (3 levers at once).
//   This is the clean test:
//  - NT=512 (8 waves), TBLK=32 queries, 512 attn blocks.
//  - K staged in the SAME two 128-d halves, SAME LSTR=132 mapping as v8/v11
//    (verified conflict-free). ks 33.8KB + p_lds 32x68 = 8.7KB -> 42.5KB
//    -> 3 blocks/CU x 8 waves = 24 waves/CU = 6 waves/SIMD (v11: 4).
//    More concurrent PV V-streams per SIMD = the latency-hiding we lack.
//  - alignment strip via the barrier-protected LDS transpose (v8/v11 style,
//    NOT v12's register strip): full 128B contiguous lines per window row.
//  - zero-role blocks (240, first in dispatch) and hoisted Q->R copy
//    unchanged from v11. Summation order unchanged (absmax ~0.00195).

#define BB 16
#define TT 1024
#define NN 1024
#define DD 256
#define WIN 64
#define TBLK 32          // queries per attn block
#define NT 512           // 8 waves, 4 queries each
#define NZ 240           // zero-streaming blocks (16 batches x 15)

#define R_ELEMS   (16u*1024u*512u)        // 8388608
#define ALN_ELEMS (16u*1024u*1024u)       // 16777216

#define LSTR 132         // LDS row stride (floats); 132%32==4 -> conflict-free b128

__global__ __launch_bounds__(NT, 6) void attn_v13(
    const float* __restrict__ Q, const float* __restrict__ K,
    const float* __restrict__ V, const int* __restrict__ prev_in,
    float* __restrict__ out)
{
    __shared__ float ks[WIN * LSTR];        // 33792 B: K half-tile
    __shared__ float p_lds[TBLK][WIN + 4];  //  8704 B: probabilities [t][j]

    float* Rout   = out;
    float* aligns = out + R_ELEMS;
    float* maxatt = out + R_ELEMS + ALN_ELEMS;

    const int tid = threadIdx.x;

    // ================= role 1: zero-streaming blocks =================
    if (blockIdx.x < NZ) {
        const int zb    = blockIdx.x;
        const int b     = zb / 15;          // 15 blocks per batch
        const int chunk = zb % 15;          // 64 rows each
        const int prev  = prev_in[b];
        float4* zbase = (float4*)(aligns + (size_t)b * NN * TT);
        const float4 z = make_float4(0.f, 0.f, 0.f, 0.f);
        #pragma unroll 8
        for (int r = 0; r < 32; ++r) {      // 512 threads cover 2 rows/iter
            int idx = chunk * 64 + 2 * r + (tid >> 8);  // 0..959 among non-window
            int n   = idx < prev ? idx : idx + WIN;
            zbase[(size_t)n * 256 + (tid & 255)] = z;   // 4KB contiguous per row
        }
        return;                             // wave dies; stores drain async
    }

    // ================= role 2: attention blocks (v8 core, 8 waves) ==========
    const int aid  = blockIdx.x - NZ;       // 0..511
    const int lane = tid & 63;
    const int w    = __builtin_amdgcn_readfirstlane(tid >> 6);  // wave 0..7
    const int b    = aid >> 5;              // 32 blocks per batch
    const int t0   = (aid & 31) * TBLK;
    const int prev = prev_in[b];

    const float* qb = Q + ((size_t)b * TT + t0 + 4 * w) * DD;   // wave-uniform base

    // ---- hoisted Q copy: warms L2 for the QK scalar stream ----
    #pragma unroll
    for (int t = 0; t < 4; ++t) {
        float4 qv = ((const float4*)(qb + t * DD))[lane];
        float* Rrow = Rout + ((size_t)b * TT + t0 + 4 * w + t) * (2 * DD);
        ((float4*)(Rrow + DD))[lane] = qv;
    }

    // ================= QK^T over two 128-d halves =================
    float acc[4] = {0.f, 0.f, 0.f, 0.f};
    #pragma unroll
    for (int h = 0; h < 2; ++h) {
        if (h) __syncthreads();             // h0 readers done before restage
        const float4* Ksrc = (const float4*)(K + ((size_t)b * NN + prev) * DD + h * 128);
        #pragma unroll
        for (int k = 0; k < 4; ++k) {
            int t4 = tid + k * NT;          // 0..2047 float4 chunks
            int r = t4 >> 5, c = t4 & 31;
            float4 v = Ksrc[(size_t)r * 64 + c];
            *(float4*)&ks[r * LSTR + c * 4] = v;
        }
        __syncthreads();

        const float* qh = qb + h * 128;
        #pragma unroll 8
        for (int d4 = 0; d4 < 32; ++d4) {
            float4 kk = *(const float4*)&ks[lane * LSTR + d4 * 4];  // conflict-free b128
            #pragma unroll
            for (int t = 0; t < 4; ++t) {
                float4 q = ((const float4*)(qh + t * DD))[d4];      // wave-uniform
                acc[t] = fmaf(q.x, kk.x, fmaf(q.y, kk.y, fmaf(q.z, kk.z, fmaf(q.w, kk.w, acc[t]))));
            }
        }
    }

    // ================= softmax + argmax (wave-local), p -> LDS ===========
    #pragma unroll
    for (int tt = 0; tt < 4; ++tt) {
        const int t = 4 * w + tt;
        float v = acc[tt] * 0.0625f;        // 1/sqrt(256)

        float m = v;
        #pragma unroll
        for (int off = 32; off; off >>= 1) m = fmaxf(m, __shfl_xor(m, off));

        float e = expf(v - m);
        float s = e;
        #pragma unroll
        for (int off = 32; off; off >>= 1) s += __shfl_xor(s, off);

        p_lds[t][lane] = e / s;

        float av = v; int ai = lane;
        #pragma unroll
        for (int off = 32; off; off >>= 1) {
            float ov = __shfl_xor(av, off);
            int   oi = __shfl_xor(ai, off);
            if (ov > av || (ov == av && oi < ai)) { av = ov; ai = oi; }
        }
        if (lane == 0) maxatt[(size_t)b * TT + t0 + t] = (float)(prev + ai);
    }
    __syncthreads();                        // all 32 p rows visible

    // ===== window-row alignment strip: 64 rows x 32 floats (128B lines) ====
    // Zero blocks never touch these rows -> written exactly once.
    {
        const int j = tid >> 3, cg = tid & 7;   // 8 threads per window row
        float4 v;
        v.x = p_lds[cg * 4 + 0][j];
        v.y = p_lds[cg * 4 + 1][j];
        v.z = p_lds[cg * 4 + 2][j];
        v.w = p_lds[cg * 4 + 3][j];
        *(float4*)(aligns + ((size_t)b * NN + prev + j) * TT + t0 + cg * 4) = v;
    }

    // ================= PV direct from global (L2-hot V) ==================
    // lane = d-chunk (64 x float4 = 256 d); reads own wave's p rows.
    {
        const float4* V4 = (const float4*)(V + ((size_t)b * NN + prev) * DD);
        float4 o[4];
        #pragma unroll
        for (int t = 0; t < 4; ++t) o[t] = make_float4(0.f, 0.f, 0.f, 0.f);

        #pragma unroll 4
        for (int j4 = 0; j4 < WIN / 4; ++j4) {
            float4 p0 = *(const float4*)&p_lds[4 * w + 0][j4 * 4];  // uniform bcast
            float4 p1 = *(const float4*)&p_lds[4 * w + 1][j4 * 4];
            float4 p2 = *(const float4*)&p_lds[4 * w + 2][j4 * 4];
            float4 p3 = *(const float4*)&p_lds[4 * w + 3][j4 * 4];
            float4 v0 = V4[(size_t)(j4 * 4 + 0) * 64 + lane];
            float4 v1 = V4[(size_t)(j4 * 4 + 1) * 64 + lane];
            float4 v2 = V4[(size_t)(j4 * 4 + 2) * 64 + lane];
            float4 v3 = V4[(size_t)(j4 * 4 + 3) * 64 + lane];
            #define ACC4(o_, p_) \
                o_.x = fmaf(p_.x, v0.x, fmaf(p_.y, v1.x, fmaf(p_.z, v2.x, fmaf(p_.w, v3.x, o_.x)))); \
                o_.y = fmaf(p_.x, v0.y, fmaf(p_.y, v1.y, fmaf(p_.z, v2.y, fmaf(p_.w, v3.y, o_.y)))); \
                o_.z = fmaf(p_.x, v0.z, fmaf(p_.y, v1.z, fmaf(p_.z, v2.z, fmaf(p_.w, v3.z, o_.z)))); \
                o_.w = fmaf(p_.x, v0.w, fmaf(p_.y, v1.w, fmaf(p_.z, v2.w, fmaf(p_.w, v3.w, o_.w))));
            ACC4(o[0], p0) ACC4(o[1], p1) ACC4(o[2], p2) ACC4(o[3], p3)
            #undef ACC4
        }

        #pragma unroll
        for (int t = 0; t < 4; ++t) {
            float* Rrow = Rout + ((size_t)b * TT + t0 + 4 * w + t) * (2 * DD);
            ((float4*)Rrow)[lane] = o[t];   // A@V (Q half already written)
        }
    }
}

extern "C" void kernel_launch(void* const* d_in, const int* in_sizes, int n_in,
                              void* d_out, int out_size, void* d_ws, size_t ws_size,
                              hipStream_t stream) {
    const float* Q = (const float*)d_in[0];
    const float* K = (const float*)d_in[1];
    const float* V = (const float*)d_in[2];
    const int* prev = (const int*)d_in[3];
    float* out = (float*)d_out;

    // single launch: 240 zero-streaming blocks first, then 512 attn blocks
    attn_v13<<<NZ + BB * TT / TBLK, NT, 0, stream>>>(Q, K, V, prev, out);
}

// Round 8
// 158.737 us; speedup vs baseline: 1.3366x; 1.0384x over previous
//
#include <hip/hip_runtime.h>

// B=16, T=1024, N=1024, D=256, WIN=64
// outputs (flat): R (B,T,2D) = [A@V, Q]   : 8388608 f32
//                 alignments (B,N,T) = A^T: 16777216 f32
//                 max_att (B,T)           : 16384 f32
//
// v14b = v11 (best: 160.3us total, attn ~42us) + ONE lever: non-temporal
// stores on all outputs. (v14 failed to compile: __builtin_nontemporal_store
// rejects HIP_vector_type float4* — use a native ext_vector_type(4) float.)
//   Evidence: v12's FETCH explosion (33->123MB = exactly the 67MB V + K
//   windows refetched per block) proved streaming-output write-allocate
//   evicts the shared K/V windows from L2. Even v11 carries ~15MB of
//   refetch (FETCH 33MB vs 18MB compulsory) and PV's V-loads compete with
//   write-allocate fills. All outputs (R, aligns, maxatt, zeros) are
//   write-once never-read -> nt bit: no L2 allocation, K/V/Q stay hot,
//   zero drain goes straight to HBM.
//   Structure, grid, barriers, summation order: v11 verbatim.

#define BB 16
#define TT 1024
#define NN 1024
#define DD 256
#define WIN 64
#define TBLK 16          // queries per attn block
#define NT 256           // 4 waves, 4 queries each
#define NZ 240           // zero-streaming blocks (16 batches x 15)

#define R_ELEMS   (16u*1024u*512u)        // 8388608
#define ALN_ELEMS (16u*1024u*1024u)       // 16777216

#define LSTR 132         // LDS row stride (dwords); 132%32==4 -> conflict-free b128

typedef float f32x4 __attribute__((ext_vector_type(4)));

__device__ __forceinline__ void nts4(void* p, float4 v) {
    f32x4 nv;
    nv.x = v.x; nv.y = v.y; nv.z = v.z; nv.w = v.w;
    __builtin_nontemporal_store(nv, (f32x4*)p);
}

__global__ __launch_bounds__(NT, 4) void attn_v14(
    const float* __restrict__ Q, const float* __restrict__ K,
    const float* __restrict__ V, const int* __restrict__ prev_in,
    float* __restrict__ out)
{
    __shared__ float ks[WIN * LSTR];        // 33792 B: K half-tile
    __shared__ float p_lds[TBLK][WIN + 4];  // 4352 B : probabilities [t][j]

    float* Rout   = out;
    float* aligns = out + R_ELEMS;
    float* maxatt = out + R_ELEMS + ALN_ELEMS;

    const int tid = threadIdx.x;

    // ================= role 1: zero-streaming blocks =================
    if (blockIdx.x < NZ) {
        const int zb    = blockIdx.x;
        const int b     = zb / 15;          // 15 blocks per batch
        const int chunk = zb % 15;          // 64 rows each
        const int prev  = prev_in[b];
        float* zbase = aligns + (size_t)b * NN * TT;
        const float4 z = make_float4(0.f, 0.f, 0.f, 0.f);
        #pragma unroll 8
        for (int r = 0; r < 64; ++r) {
            int idx = chunk * 64 + r;          // 0..959 among non-window rows
            int n   = idx < prev ? idx : idx + WIN;
            nts4(zbase + (size_t)n * 1024 + tid * 4, z);  // nt: no L2 allocation
        }
        return;                                // wave dies; stores drain async
    }

    // ================= role 2: attention blocks (v8 core) =================
    const int aid  = blockIdx.x - NZ;
    const int lane = tid & 63;
    const int w    = __builtin_amdgcn_readfirstlane(tid >> 6);  // wave 0..3
    const int b    = aid >> 6;              // 64 blocks per batch
    const int t0   = (aid & 63) * TBLK;
    const int prev = prev_in[b];

    const float* qb = Q + ((size_t)b * TT + t0 + 4 * w) * DD;   // wave-uniform base

    // ---- hoisted Q copy (nt store: R never re-read) ----
    #pragma unroll
    for (int t = 0; t < 4; ++t) {
        float4 qv = ((const float4*)(qb + t * DD))[lane];
        float* Rrow = Rout + ((size_t)b * TT + t0 + 4 * w + t) * (2 * DD);
        nts4(Rrow + DD + lane * 4, qv);
    }

    // ================= QK^T over two 128-d halves =================
    float acc[4] = {0.f, 0.f, 0.f, 0.f};
    #pragma unroll
    for (int h = 0; h < 2; ++h) {
        if (h) __syncthreads();             // h0 readers done before restage
        const float4* Ksrc = (const float4*)(K + ((size_t)b * NN + prev) * DD + h * 128);
        #pragma unroll
        for (int k = 0; k < 8; ++k) {
            int t4 = tid + k * NT;          // 0..2047 float4 chunks
            int r = t4 >> 5, c = t4 & 31;
            float4 v = Ksrc[(size_t)r * 64 + c];
            *(float4*)&ks[r * LSTR + c * 4] = v;
        }
        __syncthreads();

        const float* qh = qb + h * 128;
        #pragma unroll 8
        for (int d4 = 0; d4 < 32; ++d4) {
            float4 kk = *(const float4*)&ks[lane * LSTR + d4 * 4];  // conflict-free b128
            #pragma unroll
            for (int t = 0; t < 4; ++t) {
                float4 q = ((const float4*)(qh + t * DD))[d4];      // wave-uniform
                acc[t] = fmaf(q.x, kk.x, fmaf(q.y, kk.y, fmaf(q.z, kk.z, fmaf(q.w, kk.w, acc[t]))));
            }
        }
    }

    // ================= softmax + argmax (wave-local), p -> LDS ===========
    #pragma unroll
    for (int t = 0; t < 4; ++t) {
        float v = acc[t] * 0.0625f;         // 1/sqrt(256)

        float m = v;
        #pragma unroll
        for (int off = 32; off; off >>= 1) m = fmaxf(m, __shfl_xor(m, off));

        float e = expf(v - m);
        float s = e;
        #pragma unroll
        for (int off = 32; off; off >>= 1) s += __shfl_xor(s, off);

        p_lds[4 * w + t][lane] = e / s;

        float av = v; int ai = lane;
        #pragma unroll
        for (int off = 32; off; off >>= 1) {
            float ov = __shfl_xor(av, off);
            int   oi = __shfl_xor(ai, off);
            if (ov > av || (ov == av && oi < ai)) { av = ov; ai = oi; }
        }
        if (lane == 0)
            __builtin_nontemporal_store((float)(prev + ai),
                                        &maxatt[(size_t)b * TT + t0 + 4 * w + t]);
    }
    __syncthreads();                        // all 16 p rows visible

    // ===== window-row alignment strip: 64 rows x 16 floats (64B lines) ====
    // Zero blocks never touch these rows -> written exactly once.
    {
        const int j = tid >> 2, cg = tid & 3;
        float4 v;
        v.x = p_lds[cg * 4 + 0][j];
        v.y = p_lds[cg * 4 + 1][j];
        v.z = p_lds[cg * 4 + 2][j];
        v.w = p_lds[cg * 4 + 3][j];
        nts4(aligns + ((size_t)b * NN + prev + j) * TT + t0 + cg * 4, v);
    }

    // ================= PV direct from global (L2-hot V) ==================
    // lane = d-chunk (64 x float4 = 256 d); reads own wave's p rows.
    {
        const float4* V4 = (const float4*)(V + ((size_t)b * NN + prev) * DD);
        float4 o[4];
        #pragma unroll
        for (int t = 0; t < 4; ++t) o[t] = make_float4(0.f, 0.f, 0.f, 0.f);

        #pragma unroll 4
        for (int j4 = 0; j4 < WIN / 4; ++j4) {
            float4 p0 = *(const float4*)&p_lds[4 * w + 0][j4 * 4];  // uniform bcast
            float4 p1 = *(const float4*)&p_lds[4 * w + 1][j4 * 4];
            float4 p2 = *(const float4*)&p_lds[4 * w + 2][j4 * 4];
            float4 p3 = *(const float4*)&p_lds[4 * w + 3][j4 * 4];
            float4 v0 = V4[(size_t)(j4 * 4 + 0) * 64 + lane];
            float4 v1 = V4[(size_t)(j4 * 4 + 1) * 64 + lane];
            float4 v2 = V4[(size_t)(j4 * 4 + 2) * 64 + lane];
            float4 v3 = V4[(size_t)(j4 * 4 + 3) * 64 + lane];
            #define ACC4(o_, p_) \
                o_.x = fmaf(p_.x, v0.x, fmaf(p_.y, v1.x, fmaf(p_.z, v2.x, fmaf(p_.w, v3.x, o_.x)))); \
                o_.y = fmaf(p_.x, v0.y, fmaf(p_.y, v1.y, fmaf(p_.z, v2.y, fmaf(p_.w, v3.y, o_.y)))); \
                o_.z = fmaf(p_.x, v0.z, fmaf(p_.y, v1.z, fmaf(p_.z, v2.z, fmaf(p_.w, v3.z, o_.z)))); \
                o_.w = fmaf(p_.x, v0.w, fmaf(p_.y, v1.w, fmaf(p_.z, v2.w, fmaf(p_.w, v3.w, o_.w))));
            ACC4(o[0], p0) ACC4(o[1], p1) ACC4(o[2], p2) ACC4(o[3], p3)
            #undef ACC4
        }

        #pragma unroll
        for (int t = 0; t < 4; ++t) {
            float* Rrow = Rout + ((size_t)b * TT + t0 + 4 * w + t) * (2 * DD);
            nts4(Rrow + lane * 4, o[t]);    // A@V (Q half already written)
        }
    }
}

extern "C" void kernel_launch(void* const* d_in, const int* in_sizes, int n_in,
                              void* d_out, int out_size, void* d_ws, size_t ws_size,
                              hipStream_t stream) {
    const float* Q = (const float*)d_in[0];
    const float* K = (const float*)d_in[1];
    const float* V = (const float*)d_in[2];
    const int* prev = (const int*)d_in[3];
    float* out = (float*)d_out;

    // single launch: 240 zero-streaming blocks first, then 1024 attn blocks
    attn_v14<<<NZ + BB * TT / TBLK, NT, 0, stream>>>(Q, K, V, prev, out);
}